// Round 1
// baseline (147.048 us; speedup 1.0000x reference)
//
#include <hip/hip_runtime.h>

typedef unsigned short u16;
typedef short bf16x8 __attribute__((ext_vector_type(8)));
typedef float f32x4 __attribute__((ext_vector_type(4)));
typedef u16 u16x4 __attribute__((ext_vector_type(4)));

__device__ __forceinline__ float b2f(u16 h) {
  unsigned u = ((unsigned)h) << 16;
  return __builtin_bit_cast(float, u);
}
__device__ __forceinline__ u16 f2b(float f) {
  unsigned u = __builtin_bit_cast(unsigned, f);
  u = u + 0x7fffu + ((u >> 16) & 1u);   // round-to-nearest-even
  return (u16)(u >> 16);
}
__device__ __forceinline__ void gld_lds16(const void* g, void* l) {
  __builtin_amdgcn_global_load_lds(
      (__attribute__((address_space(1))) void*)(g),
      (__attribute__((address_space(3))) void*)(l), 16, 0, 0);
}

// ---------------------------------------------------------------------------
// prep_w: fp32 [o][c] weights -> bf16 in MFMA-A staging layout
//         [kchunk(8)][kgroup(4)][m(256)][8]  (stage-major, 16 KB per kchunk)
// layers: 0,1 = post_w[0],post_w[1] ; 2,3,4 = pre_w[0..2]
// ---------------------------------------------------------------------------
__global__ void dense_edge_prep_w(const float* __restrict__ pre_w,
                                  const float* __restrict__ post_w,
                                  u16* __restrict__ wdst) {
  const int id = blockIdx.x * 256 + threadIdx.x;  // 40960 slots of 8 elems
  const int layer = id >> 13;
  const int sid = id & 8191;
  const int m = sid >> 5;
  const int s8 = sid & 31;
  const float* src;
  u16* dst;
  if (layer < 2) { src = post_w + layer * 65536; dst = wdst + layer * 65536; }
  else           { src = pre_w + (layer - 2) * 65536; dst = wdst + 131072 + (layer - 2) * 65536; }
  f32x4 a = *(const f32x4*)(src + m * 256 + s8 * 8);
  f32x4 c = *(const f32x4*)(src + m * 256 + s8 * 8 + 4);
  bf16x8 o;
#pragma unroll
  for (int j = 0; j < 4; j++) o[j] = (short)f2b(a[j]);
#pragma unroll
  for (int j = 0; j < 4; j++) o[4 + j] = (short)f2b(c[j]);
  *(bf16x8*)(dst + (s8 * 256 + m) * 8) = o;
}

// ---------------------------------------------------------------------------
// prep_x: x [2][256][1024] fp32 -> x_t [node=2048][c=256] bf16 (LDS transpose)
// ---------------------------------------------------------------------------
__global__ void dense_edge_prep_x(const float* __restrict__ x, u16* __restrict__ xt) {
  __shared__ float tile[32 * 65];
  const int t = threadIdx.x;
  const int blk = blockIdx.x;  // 2 b x 8 ctile x 16 hwtile = 256
  const int b = blk >> 7;
  const int ct = (blk >> 4) & 7;
  const int ht = blk & 15;
  const int c0 = ct * 32, hw0 = ht * 64;
#pragma unroll
  for (int rep = 0; rep < 8; rep++) {
    const int idx = rep * 256 + t;
    const int cl = idx >> 6, hl = idx & 63;
    tile[cl * 65 + hl] = x[(b * 256 + c0 + cl) * 1024 + hw0 + hl];
  }
  __syncthreads();
  const int hl = t >> 2, c8 = t & 3;
  bf16x8 o;
#pragma unroll
  for (int i = 0; i < 8; i++) o[i] = (short)f2b(tile[(c8 * 8 + i) * 65 + hl]);
  *(bf16x8*)(xt + (b * 1024 + hw0 + hl) * 256 + c0 + c8 * 8) = o;
}

// ---------------------------------------------------------------------------
// pre_gemm: 3-layer 1x1-conv chain on 2048 nodes, bf16 MFMA.
// Block = 16 nodes. D[o][node]: A = W (prepped layout, read from global/L2),
// B = features [kg][n][8] in LDS ping-pong. Output flat[node][c] bf16.
// ---------------------------------------------------------------------------
__global__ __launch_bounds__(256, 2) void dense_edge_pre(
    const u16* __restrict__ xt, const u16* __restrict__ wpre,
    const float* __restrict__ preb, u16* __restrict__ flat) {
  __shared__ u16 feat[2][4096];  // [32 s8][16 n][8] each
  const int t = threadIdx.x;
  const int wv = t >> 6, ln = t & 63;
  const int nb = blockIdx.x * 16;
  const int q4 = ln >> 4, r15 = ln & 15;

#pragma unroll
  for (int i = 0; i < 2; i++) {
    const int slot = wv * 128 + i * 64 + ln;
    const int s8 = slot >> 4, nl = slot & 15;
    gld_lds16(xt + (nb + nl) * 256 + s8 * 8, &feat[0][slot * 8]);
  }
  __syncthreads();

#pragma unroll
  for (int l = 0; l < 3; l++) {
    const u16* wl = wpre + l * 65536;
    f32x4 acc[4];
    f32x4 zero = {0.f, 0.f, 0.f, 0.f};
#pragma unroll
    for (int mt = 0; mt < 4; mt++) acc[mt] = zero;
#pragma unroll
    for (int s = 0; s < 8; s++) {
      bf16x8 bv = *(const bf16x8*)(&feat[l & 1][((s * 4 + q4) * 16 + r15) * 8]);
#pragma unroll
      for (int mt = 0; mt < 4; mt++) {
        bf16x8 av = *(const bf16x8*)(wl + ((s * 4 + q4) * 256 + wv * 64 + mt * 16 + r15) * 8);
        acc[mt] = __builtin_amdgcn_mfma_f32_16x16x32_bf16(av, bv, acc[mt], 0, 0, 0);
      }
    }
    if (l < 2) {
#pragma unroll
      for (int mt = 0; mt < 4; mt++) {
        const int o = wv * 64 + mt * 16 + q4 * 4;
        f32x4 bb = *(const f32x4*)(preb + l * 256 + o);
        u16x4 pk;
#pragma unroll
        for (int r = 0; r < 4; r++) {
          float v = fmaxf(acc[mt][r] + bb[r], 0.f);
          pk[r] = f2b(v);
        }
        *(u16x4*)(&feat[(l + 1) & 1][((o >> 3) * 16 + r15) * 8 + (o & 7)]) = pk;
      }
      __syncthreads();
    } else {
#pragma unroll
      for (int mt = 0; mt < 4; mt++) {
        const int o = wv * 64 + mt * 16 + q4 * 4;
        f32x4 bb = *(const f32x4*)(preb + 512 + o);
        u16x4 pk;
#pragma unroll
        for (int r = 0; r < 4; r++) pk[r] = f2b(acc[mt][r] + bb[r]);  // no relu
        *(u16x4*)(flat + (nb + r15) * 256 + o) = pk;
      }
    }
  }
}

// ---------------------------------------------------------------------------
// main fused kernel: per block = one (b, 8p x 8q) tile, Nt = 64 columns.
// XX build -> GEMM1(W1,relu,b1) -> GEMM2(W2,relu,b2) -> W3 epilogue.
// LDS: xxbuf 32 KB ([c>>3 slot(32)][n(64)][8] bf16, reused for T1/T2),
//      wbuf 2x16 KB double-buffered weight chunks via global_load_lds(16B).
// ---------------------------------------------------------------------------
__global__ __launch_bounds__(256, 2) void dense_edge_main(
    const u16* __restrict__ flat, const int* __restrict__ pidx,
    const int* __restrict__ cidx, const u16* __restrict__ w1p,
    const u16* __restrict__ w2p, const float* __restrict__ b1,
    const float* __restrict__ b2, const float* __restrict__ w3,
    const float* __restrict__ b3, float* __restrict__ out) {
  __shared__ u16 xxbuf[16384];     // 32 KB
  __shared__ u16 wbuf[2][8192];    // 2 x 16 KB

  const int t = threadIdx.x;
  const int wv = t >> 6;
  const int ln = t & 63;
  const int blk = blockIdx.x;
  const int b = blk >> 10;
  const int pt = (blk >> 5) & 31;
  const int qt = blk & 31;
  const int p0 = pt * 8, q0 = qt * 8;
  const int q4 = ln >> 4, r15 = ln & 15;

  // issue W1 stage 0 -> wbuf[0] (async, overlaps XX build)
  {
    const int off = wv * 2048 + ln * 8;
    gld_lds16(w1p + off, &wbuf[0][off]);
    gld_lds16(w1p + off + 512, &wbuf[0][off + 512]);
    gld_lds16(w1p + off + 1024, &wbuf[0][off + 1024]);
    gld_lds16(w1p + off + 1536, &wbuf[0][off + 1536]);
  }

  // build XX tile: thread handles n = ln, c-block = wv (64 channels, 8 slots)
  {
    const int n = t & 63;
    const int cb = t >> 6;
    const int pn = pidx[b * 256 + p0 + (n >> 3)];
    const int qn = cidx[b * 256 + q0 + (n & 7)];
    const u16* prow = flat + pn * 256 + cb * 64;
    const u16* qrow = flat + qn * 256 + cb * 64;
#pragma unroll
    for (int i = 0; i < 8; i++) {
      bf16x8 av = *(const bf16x8*)(prow + i * 8);
      bf16x8 bv = *(const bf16x8*)(qrow + i * 8);
      bf16x8 ov;
#pragma unroll
      for (int j = 0; j < 8; j++) {
        float d = b2f((u16)av[j]) - b2f((u16)bv[j]);
        ov[j] = (short)f2b(d * d);
      }
      const int s8 = cb * 8 + i;
      *(bf16x8*)(xxbuf + (s8 * 64 + n) * 8) = ov;
    }
  }

  f32x4 acc[4][4];
  {
    f32x4 zero = {0.f, 0.f, 0.f, 0.f};
#pragma unroll
    for (int mt = 0; mt < 4; mt++)
#pragma unroll
      for (int nt = 0; nt < 4; nt++) acc[mt][nt] = zero;
  }

  __syncthreads();  // stage0 drained + XX visible

#pragma unroll
  for (int s = 0; s < 16; s++) {
    if (s == 8) {
      // GEMM1 -> T1 (relu + b1) into xxbuf, then GEMM2 resumes
      __syncthreads();
#pragma unroll
      for (int mt = 0; mt < 4; mt++) {
        const int o = wv * 64 + mt * 16 + q4 * 4;
        f32x4 bb = *(const f32x4*)(b1 + o);
#pragma unroll
        for (int nt = 0; nt < 4; nt++) {
          const int nn = nt * 16 + r15;
          u16x4 pk;
#pragma unroll
          for (int r = 0; r < 4; r++) {
            float v = fmaxf(acc[mt][nt][r] + bb[r], 0.f);
            pk[r] = f2b(v);
            acc[mt][nt][r] = 0.f;
          }
          *(u16x4*)(xxbuf + ((o >> 3) * 64 + nn) * 8 + (o & 7)) = pk;
        }
      }
      __syncthreads();
    } else if (s) {
      __syncthreads();
    }
    if (s + 1 < 16) {  // prefetch next weight chunk
      const int sn = s + 1;
      const u16* src = (sn < 8) ? (w1p + sn * 8192) : (w2p + (sn - 8) * 8192);
      u16* dst = wbuf[sn & 1];
      const int off = wv * 2048 + ln * 8;
      gld_lds16(src + off, dst + off);
      gld_lds16(src + off + 512, dst + off + 512);
      gld_lds16(src + off + 1024, dst + off + 1024);
      gld_lds16(src + off + 1536, dst + off + 1536);
    }
    {
      const u16* wb = wbuf[s & 1];
      const int s8b = (s & 7) * 4;
      bf16x8 af[4], bfr[4];
#pragma unroll
      for (int mt = 0; mt < 4; mt++)
        af[mt] = *(const bf16x8*)(wb + (q4 * 256 + wv * 64 + mt * 16 + r15) * 8);
#pragma unroll
      for (int nt = 0; nt < 4; nt++)
        bfr[nt] = *(const bf16x8*)(xxbuf + ((s8b + q4) * 64 + nt * 16 + r15) * 8);
#pragma unroll
      for (int mt = 0; mt < 4; mt++)
#pragma unroll
        for (int nt = 0; nt < 4; nt++)
          acc[mt][nt] = __builtin_amdgcn_mfma_f32_16x16x32_bf16(af[mt], bfr[nt], acc[mt][nt], 0, 0, 0);
    }
  }

  // T2 writeback (relu + b2)
  __syncthreads();
#pragma unroll
  for (int mt = 0; mt < 4; mt++) {
    const int o = wv * 64 + mt * 16 + q4 * 4;
    f32x4 bb = *(const f32x4*)(b2 + o);
#pragma unroll
    for (int nt = 0; nt < 4; nt++) {
      const int nn = nt * 16 + r15;
      u16x4 pk;
#pragma unroll
      for (int r = 0; r < 4; r++) {
        float v = fmaxf(acc[mt][nt][r] + bb[r], 0.f);
        pk[r] = f2b(v);
      }
      *(u16x4*)(xxbuf + ((o >> 3) * 64 + nn) * 8 + (o & 7)) = pk;
    }
  }
  __syncthreads();

  // final layer: out[o3][n] = sum_c W3[o3][c] * T2[c][n] + b3[o3]
  {
    const int o3 = t >> 7;
    const int nn = (t >> 1) & 63;
    const int hf = t & 1;  // half of c-range; partner lane = t^1 (same wave)
    const float* w3r = w3 + o3 * 256 + hf * 128;
    float sum = 0.f;
#pragma unroll
    for (int s8 = 0; s8 < 16; s8++) {
      const int slot = hf * 16 + s8;
      bf16x8 tv = *(const bf16x8*)(xxbuf + (slot * 64 + nn) * 8);
      f32x4 wa = *(const f32x4*)(w3r + s8 * 8);
      f32x4 wc = *(const f32x4*)(w3r + s8 * 8 + 4);
#pragma unroll
      for (int j = 0; j < 4; j++) sum += b2f((u16)tv[j]) * wa[j];
#pragma unroll
      for (int j = 0; j < 4; j++) sum += b2f((u16)tv[4 + j]) * wc[j];
    }
    sum += __shfl_xor(sum, 1, 64);
    if (hf == 0) {
      out[((b * 2 + o3) * 256 + p0 + (nn >> 3)) * 256 + q0 + (nn & 7)] = sum + b3[o3];
    }
  }
}

// ---------------------------------------------------------------------------
extern "C" void kernel_launch(void* const* d_in, const int* in_sizes, int n_in,
                              void* d_out, int out_size, void* d_ws, size_t ws_size,
                              hipStream_t stream) {
  (void)in_sizes; (void)n_in; (void)out_size; (void)ws_size;
  const float* x          = (const float*)d_in[0];
  const int*   pidx       = (const int*)d_in[1];
  const int*   cidx       = (const int*)d_in[2];
  const float* pre_w      = (const float*)d_in[3];
  const float* pre_b      = (const float*)d_in[4];
  const float* post_w     = (const float*)d_in[5];
  const float* post_b     = (const float*)d_in[6];
  const float* post_out_w = (const float*)d_in[7];
  const float* post_out_b = (const float*)d_in[8];
  float* out = (float*)d_out;

  u16* ws   = (u16*)d_ws;
  u16* w1p  = ws;             // post_w[0] prepped: 65536 u16
  u16* w2p  = ws + 65536;     // post_w[1] prepped
  u16* wpre = ws + 131072;    // pre_w[0..2] prepped: 3*65536
  u16* xt   = ws + 327680;    // x_t bf16 [2048][256]
  u16* flat = ws + 851968;    // node features bf16 [2048][256]
  // total ws use: 1376256 u16 = 2.75 MB

  dense_edge_prep_w<<<160, 256, 0, stream>>>(pre_w, post_w, ws);
  dense_edge_prep_x<<<256, 256, 0, stream>>>(x, xt);
  dense_edge_pre<<<128, 256, 0, stream>>>(xt, wpre, pre_b, flat);
  dense_edge_main<<<2048, 256, 0, stream>>>(flat, pidx, cidx, w1p, w2p,
                                            post_b, post_b + 256,
                                            post_out_w, post_out_b, out);
}